// Round 1
// baseline (467.924 us; speedup 1.0000x reference)
//
#include <hip/hip_runtime.h>
#include <hip/hip_bf16.h>

// Sizes fixed by the reference
#define B_ 16
#define H_ 2048
#define W_ 128

using f32x4  = __attribute__((ext_vector_type(4))) float;
using bf16x8 = __attribute__((ext_vector_type(8))) short;

// ---------------------------------------------------------------------------
// K0a: per-row sums s[b,h] = sum_w x, plus bf16 copy Xb[b][h][w]
// one wave per row, 4 rows per block
// ---------------------------------------------------------------------------
__global__ __launch_bounds__(256) void prep_rows(const float* __restrict__ x,
                                                 __hip_bfloat16* __restrict__ Xb,
                                                 float* __restrict__ s) {
    int wave = threadIdx.x >> 6;
    int lane = threadIdx.x & 63;
    int row  = blockIdx.x * 4 + wave;                  // 0 .. B_*H_-1
    const float2 v = *reinterpret_cast<const float2*>(x + (size_t)row * W_ + lane * 2);
    __hip_bfloat162 h2;
    h2.x = __float2bfloat16(v.x);
    h2.y = __float2bfloat16(v.y);
    *reinterpret_cast<__hip_bfloat162*>(Xb + (size_t)row * W_ + lane * 2) = h2;
    float sum = v.x + v.y;
#pragma unroll
    for (int m = 1; m < 64; m <<= 1) sum += __shfl_xor(sum, m, 64);
    if (lane == 0) s[row] = sum;
}

// ---------------------------------------------------------------------------
// K0b: XT[b][w][h] = bf16(x[b][h][w])  (64x64 LDS tile transpose)
// grid: b*32*2 blocks (hb 0..31, wb 0..1), 256 threads
// ---------------------------------------------------------------------------
__global__ __launch_bounds__(256) void prep_xt(const float* __restrict__ x,
                                               __hip_bfloat16* __restrict__ XT) {
    __shared__ float tile[64][65];
    int bid = blockIdx.x;
    int wb = bid & 1;
    int hb = (bid >> 1) & 31;
    int b  = bid >> 6;
    int h0 = hb * 64, w0 = wb * 64;
    const float* xb = x + (size_t)b * H_ * W_;
    int tx = threadIdx.x & 63, ty = threadIdx.x >> 6;
#pragma unroll
    for (int p = 0; p < 16; ++p) {
        int hl = p * 4 + ty;
        tile[hl][tx] = xb[(size_t)(h0 + hl) * W_ + w0 + tx];
    }
    __syncthreads();
    __hip_bfloat16* xt = XT + (size_t)b * W_ * H_;
#pragma unroll
    for (int p = 0; p < 16; ++p) {
        int wl = p * 4 + ty;
        xt[(size_t)(w0 + wl) * H_ + h0 + tx] = __float2bfloat16(tile[tx][wl]);
    }
}

// ---------------------------------------------------------------------------
// K1: per-row min/max of t[b,h,g] = A*S_hg + C*s_g, S = X X^T via bf16 MFMA.
// grid = B_*32 blocks, 256 threads (4 waves), wave owns 16 h-rows.
// ---------------------------------------------------------------------------
__global__ __launch_bounds__(256) void pass1_stats(
    const __hip_bfloat16* __restrict__ Xb, const float* __restrict__ s,
    const float* __restrict__ w1, const float* __restrict__ b1,
    const float* __restrict__ w2, const float* __restrict__ b2,
    float* __restrict__ mn_out, float* __restrict__ mx_out) {
    float A = 0.f, C = 0.f;
#pragma unroll
    for (int c = 0; c < 8; ++c) { A += w1[c] * w2[c]; C += b1[c] * w2[c]; }

    int wave = threadIdx.x >> 6, lane = threadIdx.x & 63;
    int q = lane >> 4, r = lane & 15;
    int b = blockIdx.x >> 5, hb = blockIdx.x & 31;
    int h0 = hb * 64 + wave * 16;

    const __hip_bfloat16* xb = Xb + (size_t)b * H_ * W_;
    const float* sb = s + b * H_;

    bf16x8 afr[4];
#pragma unroll
    for (int k = 0; k < 4; ++k)
        afr[k] = *reinterpret_cast<const bf16x8*>(xb + (size_t)(h0 + r) * W_ + k * 32 + q * 8);

    float mnv[4], mxv[4];
#pragma unroll
    for (int i = 0; i < 4; ++i) { mnv[i] = 3.4e38f; mxv[i] = -3.4e38f; }

    for (int g0 = 0; g0 < H_; g0 += 16) {
        f32x4 acc = {0.f, 0.f, 0.f, 0.f};
#pragma unroll
        for (int k = 0; k < 4; ++k) {
            bf16x8 bfr = *reinterpret_cast<const bf16x8*>(xb + (size_t)(g0 + r) * W_ + k * 32 + q * 8);
            acc = __builtin_amdgcn_mfma_f32_16x16x32_bf16(afr[k], bfr, acc, 0, 0, 0);
        }
        float sg = sb[g0 + r];
#pragma unroll
        for (int reg = 0; reg < 4; ++reg) {
            float t = A * acc[reg] + C * sg;   // D frag: col(g)=lane&15, row(h)=q*4+reg
            mnv[reg] = fminf(mnv[reg], t);
            mxv[reg] = fmaxf(mxv[reg], t);
        }
    }
#pragma unroll
    for (int reg = 0; reg < 4; ++reg) {
#pragma unroll
        for (int m = 1; m < 16; m <<= 1) {
            mnv[reg] = fminf(mnv[reg], __shfl_xor(mnv[reg], m, 64));
            mxv[reg] = fmaxf(mxv[reg], __shfl_xor(mxv[reg], m, 64));
        }
        if (r == 0) {
            int h = h0 + q * 4 + reg;
            mn_out[b * H_ + h] = mnv[reg];
            mx_out[b * H_ + h] = mxv[reg];
        }
    }
}

// ---------------------------------------------------------------------------
// K2: recompute S tile, e = exp((t-mn)/(mx-mn+eps)), Z = sum e,
//     O = P @ X via second MFMA (P through per-wave XOR-swizzled LDS),
//     out = gamma * O / Z + x.
// grid = B_*32 blocks, 256 threads (4 waves), wave owns 16 h-rows, all 128 w.
// ---------------------------------------------------------------------------
__global__ __launch_bounds__(256) void pass2_out(
    const float* __restrict__ x,
    const __hip_bfloat16* __restrict__ Xb, const __hip_bfloat16* __restrict__ XT,
    const float* __restrict__ s,
    const float* __restrict__ mn_in, const float* __restrict__ mx_in,
    const float* __restrict__ w1, const float* __restrict__ b1,
    const float* __restrict__ w2, const float* __restrict__ b2,
    const float* __restrict__ gamma, float* __restrict__ out) {
    __shared__ __hip_bfloat16 pbuf[4][512];   // per-wave 16h x 32g bf16 (swizzled)

    float A = 0.f, C = 0.f;
#pragma unroll
    for (int c = 0; c < 8; ++c) { A += w1[c] * w2[c]; C += b1[c] * w2[c]; }

    int wave = threadIdx.x >> 6, lane = threadIdx.x & 63;
    int q = lane >> 4, r = lane & 15;
    int b = blockIdx.x >> 5, hb = blockIdx.x & 31;
    int h0 = hb * 64 + wave * 16;

    const __hip_bfloat16* xb = Xb + (size_t)b * H_ * W_;
    const __hip_bfloat16* xt = XT + (size_t)b * W_ * H_;
    const float* sb = s + b * H_;

    bf16x8 afr[4];
#pragma unroll
    for (int k = 0; k < 4; ++k)
        afr[k] = *reinterpret_cast<const bf16x8*>(xb + (size_t)(h0 + r) * W_ + k * 32 + q * 8);

    // per-row softmax constants: u2 = (t - mn) * inv * log2e  (exp via exp2)
    const float LOG2E = 1.4426950408889634f;
    float c1[4], c0[4];
#pragma unroll
    for (int reg = 0; reg < 4; ++reg) {
        int h = h0 + q * 4 + reg;
        float mn = mn_in[b * H_ + h], mx = mx_in[b * H_ + h];
        float inv = LOG2E / (mx - mn + 1e-8f);
        c1[reg] = inv;
        c0[reg] = -mn * inv;
    }

    f32x4 o[8];
#pragma unroll
    for (int i = 0; i < 8; ++i) o[i] = (f32x4){0.f, 0.f, 0.f, 0.f};
    float zacc[4] = {0.f, 0.f, 0.f, 0.f};

    __hip_bfloat16* pw = pbuf[wave];

    for (int g0 = 0; g0 < H_; g0 += 32) {
#pragma unroll
        for (int nt = 0; nt < 2; ++nt) {
            f32x4 sacc = {0.f, 0.f, 0.f, 0.f};
#pragma unroll
            for (int k = 0; k < 4; ++k) {
                bf16x8 bfr = *reinterpret_cast<const bf16x8*>(xb + (size_t)(g0 + nt * 16 + r) * W_ + k * 32 + q * 8);
                sacc = __builtin_amdgcn_mfma_f32_16x16x32_bf16(afr[k], bfr, sacc, 0, 0, 0);
            }
            float sg = sb[g0 + nt * 16 + r];
            int g = nt * 16 + r;
#pragma unroll
            for (int reg = 0; reg < 4; ++reg) {
                float t = A * sacc[reg] + C * sg;
                float e = exp2f(fmaf(t, c1[reg], c0[reg]));
                zacc[reg] += e;
                int h = q * 4 + reg;
                int cc = (g >> 3) ^ ((h >> 1) & 3);            // XOR swizzle, 16B chunks
                pw[h * 32 + cc * 8 + (g & 7)] = __float2bfloat16(e);
            }
        }
        // A-operand of GEMM2 from LDS: lane m = r (h), k-group q (g)
        int cA = q ^ ((r >> 1) & 3);
        bf16x8 pa = *reinterpret_cast<const bf16x8*>(
            reinterpret_cast<const char*>(pw) + r * 64 + cA * 16);
#pragma unroll
        for (int nt2 = 0; nt2 < 8; ++nt2) {
            bf16x8 btf = *reinterpret_cast<const bf16x8*>(xt + (size_t)(nt2 * 16 + r) * H_ + g0 + q * 8);
            o[nt2] = __builtin_amdgcn_mfma_f32_16x16x32_bf16(pa, btf, o[nt2], 0, 0, 0);
        }
    }

    // reduce Z across the 16 lanes sharing each h-row
#pragma unroll
    for (int reg = 0; reg < 4; ++reg) {
#pragma unroll
        for (int m = 1; m < 16; m <<= 1) zacc[reg] += __shfl_xor(zacc[reg], m, 64);
    }

    float g_ = gamma[0];
    const float* xrow = x + (size_t)b * H_ * W_;
    float* orow = out + (size_t)b * H_ * W_;
#pragma unroll
    for (int reg = 0; reg < 4; ++reg) {
        float sc = g_ * __builtin_amdgcn_rcpf(zacc[reg]);
        int h = h0 + q * 4 + reg;
#pragma unroll
        for (int nt2 = 0; nt2 < 8; ++nt2) {
            int w = nt2 * 16 + r;
            size_t idx = (size_t)h * W_ + w;
            orow[idx] = fmaf(sc, o[nt2][reg], xrow[idx]);
        }
    }
}

// ---------------------------------------------------------------------------
extern "C" void kernel_launch(void* const* d_in, const int* in_sizes, int n_in,
                              void* d_out, int out_size, void* d_ws, size_t ws_size,
                              hipStream_t stream) {
    const float* x     = (const float*)d_in[0];
    const float* w1    = (const float*)d_in[1];
    const float* b1    = (const float*)d_in[2];
    const float* w2    = (const float*)d_in[3];
    const float* b2    = (const float*)d_in[4];
    const float* gamma = (const float*)d_in[5];
    float* out = (float*)d_out;

    char* ws = (char*)d_ws;
    const size_t XB_BYTES = (size_t)B_ * H_ * W_ * 2;   // 8 MB
    __hip_bfloat16* Xb = (__hip_bfloat16*)ws;
    __hip_bfloat16* XT = (__hip_bfloat16*)(ws + XB_BYTES);
    float* s  = (float*)(ws + 2 * XB_BYTES);
    float* mn = (float*)(ws + 2 * XB_BYTES + (size_t)B_ * H_ * 4);
    float* mx = (float*)(ws + 2 * XB_BYTES + (size_t)2 * B_ * H_ * 4);

    prep_rows<<<B_ * H_ / 4, 256, 0, stream>>>(x, Xb, s);
    prep_xt<<<B_ * 32 * 2, 256, 0, stream>>>(x, XT);
    pass1_stats<<<B_ * 32, 256, 0, stream>>>(Xb, s, w1, b1, w2, b2, mn, mx);
    pass2_out<<<B_ * 32, 256, 0, stream>>>(x, Xb, XT, s, mn, mx, w1, b1, w2, b2, gamma, out);
}